// Round 1
// baseline (13109.836 us; speedup 1.0000x reference)
//
#include <hip/hip_runtime.h>
#include <cmath>

// GRU: B=32, T=512, E=512, H=1024, fp32.
// Phase 1: xg[t*32+b][3H] = x @ w_ih^T   (big GEMM, no recurrence)
// Phase 2: persistent kernel, 256 blocks; block i owns h columns [4i,4i+4)
//          and the 12 w_hh rows {j, H+j, 2H+j} for those columns (in LDS).
//          Grid barrier per timestep via device-scope atomic counter.
// h state kept TRANSPOSED [k][b] in ws (double buffered) for coalescing.

namespace {
constexpr int BATCH  = 32;
constexpr int TSTEPS = 512;
constexpr int EDIM   = 512;
constexpr int HDIM   = 1024;
constexpr int GDIM   = 3 * HDIM;  // 3072

constexpr size_t XG_BYTES   = (size_t)BATCH * TSTEPS * GDIM * 4;  // 192 MiB
constexpr size_t HBUF_BYTES = (size_t)HDIM * BATCH * 4;           // 128 KiB
}

__device__ __forceinline__ void grid_barrier(unsigned* cnt, unsigned target)
{
    __syncthreads();
    if (threadIdx.x == 0) {
        __hip_atomic_fetch_add(cnt, 1u, __ATOMIC_RELEASE, __HIP_MEMORY_SCOPE_AGENT);
        while (__hip_atomic_load(cnt, __ATOMIC_ACQUIRE, __HIP_MEMORY_SCOPE_AGENT) < target) {
            __builtin_amdgcn_s_sleep(2);
        }
    }
    __syncthreads();
}

// ---------------- Phase 1: xg = x @ w_ih^T ----------------
// M = 16384 (m = t*32 + b), N = 3072, K = 512. 128x128 tile, 8x8 micro.
__global__ __launch_bounds__(256)
void xg_gemm_f32(const float* __restrict__ x, const float* __restrict__ w_ih,
                 float* __restrict__ xg)
{
    __shared__ float a_s[16 * 132];
    __shared__ float b_s[16 * 132];

    const int tid = threadIdx.x;
    const int n0 = blockIdx.x * 128;
    const int m0 = blockIdx.y * 128;
    const int tx = tid & 15;
    const int ty = tid >> 4;

    float acc[8][8];
    #pragma unroll
    for (int i = 0; i < 8; ++i)
        #pragma unroll
        for (int j = 0; j < 8; ++j) acc[i][j] = 0.f;

    const int r_ld = tid >> 2;         // 0..63
    const int kq4  = (tid & 3) * 4;    // 0,4,8,12

    for (int kc = 0; kc < EDIM; kc += 16) {
        __syncthreads();
        #pragma unroll
        for (int half = 0; half < 2; ++half) {
            const int r = r_ld + half * 64;
            const int m = m0 + r;
            const int bb = m & 31;       // batch
            const int tt = m >> 5;       // time
            float4 av = *(const float4*)&x[((size_t)bb * TSTEPS + tt) * EDIM + kc + kq4];
            a_s[(kq4 + 0) * 132 + r] = av.x;
            a_s[(kq4 + 1) * 132 + r] = av.y;
            a_s[(kq4 + 2) * 132 + r] = av.z;
            a_s[(kq4 + 3) * 132 + r] = av.w;
            const int n = n0 + r;
            float4 bv = *(const float4*)&w_ih[(size_t)n * EDIM + kc + kq4];
            b_s[(kq4 + 0) * 132 + r] = bv.x;
            b_s[(kq4 + 1) * 132 + r] = bv.y;
            b_s[(kq4 + 2) * 132 + r] = bv.z;
            b_s[(kq4 + 3) * 132 + r] = bv.w;
        }
        __syncthreads();
        #pragma unroll
        for (int k = 0; k < 16; ++k) {
            float a_r[8], b_r[8];
            *(float4*)&a_r[0] = *(const float4*)&a_s[k * 132 + ty * 8];
            *(float4*)&a_r[4] = *(const float4*)&a_s[k * 132 + ty * 8 + 4];
            *(float4*)&b_r[0] = *(const float4*)&b_s[k * 132 + tx * 8];
            *(float4*)&b_r[4] = *(const float4*)&b_s[k * 132 + tx * 8 + 4];
            #pragma unroll
            for (int i = 0; i < 8; ++i)
                #pragma unroll
                for (int j = 0; j < 8; ++j)
                    acc[i][j] = fmaf(a_r[i], b_r[j], acc[i][j]);
        }
    }

    #pragma unroll
    for (int i = 0; i < 8; ++i) {
        const int m = m0 + ty * 8 + i;
        float4 v0 = make_float4(acc[i][0], acc[i][1], acc[i][2], acc[i][3]);
        float4 v1 = make_float4(acc[i][4], acc[i][5], acc[i][6], acc[i][7]);
        *(float4*)&xg[(size_t)m * GDIM + n0 + tx * 8]     = v0;
        *(float4*)&xg[(size_t)m * GDIM + n0 + tx * 8 + 4] = v1;
    }
}

// ---------------- Phase 2: persistent GRU recurrence ----------------
// 256 blocks x 256 threads. Block owns j-slice [j0, j0+4).
// w_s row r = gate*4 + jl  (gate: 0=r, 1=z, 2=n), i.e. w_hh row gate*H + j0 + jl.
// Thread mapping: bgrp = tid&7 (4 batches each), jgrp = (tid>>3)&1 (2 j each),
// kseg = tid>>4 (16-way k split). acc[gate*2+jj][bb].
__global__ __launch_bounds__(256)
void gru_recurrence(const float* __restrict__ h0, const float* __restrict__ w_hh,
                    const float* __restrict__ xg, float* __restrict__ out,
                    float* __restrict__ hbufA, float* __restrict__ hbufB,
                    unsigned* __restrict__ bar)
{
    __shared__ float w_s[12 * 1024];
    __shared__ float red_s[4 * 16 * 24];

    const int tid = threadIdx.x;
    const int j0  = blockIdx.x * 4;
    const unsigned NB = gridDim.x;

    // Load this block's 12 w_hh rows into LDS (coalesced float4 per row).
    #pragma unroll
    for (int r = 0; r < 12; ++r) {
        const int gate = r >> 2;
        const int jl   = r & 3;
        float4 v = *(const float4*)&w_hh[((size_t)gate * HDIM + j0 + jl) * HDIM + tid * 4];
        *(float4*)&w_s[r * 1024 + tid * 4] = v;
    }

    // Transpose h0 -> hbufA[k][b] for our 4 k-rows.
    if (tid < 128) {
        const int k = j0 + (tid >> 5);
        const int b = tid & 31;
        hbufA[k * 32 + b] = h0[(size_t)b * HDIM + k];
    }

    unsigned phase = 1;
    grid_barrier(bar, NB * phase);

    const int bgrp = tid & 7;
    const int jgrp = (tid >> 3) & 1;
    const int kseg = tid >> 4;
    const int b0   = bgrp * 4;

    const float* wp[6];
    wp[0] = &w_s[(0 + jgrp * 2 + 0) * 1024];
    wp[1] = &w_s[(0 + jgrp * 2 + 1) * 1024];
    wp[2] = &w_s[(4 + jgrp * 2 + 0) * 1024];
    wp[3] = &w_s[(4 + jgrp * 2 + 1) * 1024];
    wp[4] = &w_s[(8 + jgrp * 2 + 0) * 1024];
    wp[5] = &w_s[(8 + jgrp * 2 + 1) * 1024];

    for (int t = 0; t < TSTEPS; ++t) {
        const float* __restrict__ hcur = (t & 1) ? hbufB : hbufA;
        float* __restrict__ hnxt       = (t & 1) ? hbufA : hbufB;

        float acc[6][4];
        #pragma unroll
        for (int g = 0; g < 6; ++g)
            #pragma unroll
            for (int b = 0; b < 4; ++b) acc[g][b] = 0.f;

        #pragma unroll 8
        for (int kk = 0; kk < 64; ++kk) {
            const int k = kk * 16 + kseg;
            const float4 h4 = *(const float4*)&hcur[k * 32 + b0];
            #pragma unroll
            for (int g = 0; g < 6; ++g) {
                const float w = wp[g][k];
                acc[g][0] = fmaf(w, h4.x, acc[g][0]);
                acc[g][1] = fmaf(w, h4.y, acc[g][1]);
                acc[g][2] = fmaf(w, h4.z, acc[g][2]);
                acc[g][3] = fmaf(w, h4.w, acc[g][3]);
            }
        }

        // Reduce over the 4 in-wave ksegs (lane bits 4,5).
        #pragma unroll
        for (int g = 0; g < 6; ++g)
            #pragma unroll
            for (int b = 0; b < 4; ++b) {
                float v = acc[g][b];
                v += __shfl_xor(v, 16, 64);
                v += __shfl_xor(v, 32, 64);
                acc[g][b] = v;
            }

        const int lane = tid & 63;
        const int wv   = tid >> 6;
        if (lane < 16) {
            #pragma unroll
            for (int g = 0; g < 6; ++g)
                #pragma unroll
                for (int b = 0; b < 4; ++b)
                    red_s[wv * 384 + lane * 24 + g * 4 + b] = acc[g][b];
        }
        __syncthreads();

        if (tid < 32) {
            const int b = tid;
            float hv[4];
            #pragma unroll
            for (int jl = 0; jl < 4; ++jl) {
                const int pos = (jl >> 1) * 8 + (b >> 2);
                const int jj  = jl & 1;
                const int bb  = b & 3;
                float hr = 0.f, hz = 0.f, hn = 0.f;
                #pragma unroll
                for (int w = 0; w < 4; ++w) {
                    const float* rs = &red_s[w * 384 + pos * 24];
                    hr += rs[(0 + jj) * 4 + bb];
                    hz += rs[(2 + jj) * 4 + bb];
                    hn += rs[(4 + jj) * 4 + bb];
                }
                const size_t xb = ((size_t)t * 32 + b) * GDIM + j0 + jl;
                const float ir  = xg[xb];
                const float iz  = xg[xb + HDIM];
                const float inn = xg[xb + 2 * HDIM];
                const float rg = 1.f / (1.f + expf(-(ir + hr)));
                const float zg = 1.f / (1.f + expf(-(iz + hz)));
                const float ng = tanhf(inn + rg * hn);
                const float hp = hcur[(j0 + jl) * 32 + b];
                const float hnew = (1.f - zg) * ng + zg * hp;
                hv[jl] = hnew;
                hnxt[(j0 + jl) * 32 + b] = hnew;
            }
            float4 o = make_float4(hv[0], hv[1], hv[2], hv[3]);
            *(float4*)&out[((size_t)b * TSTEPS + t) * HDIM + j0] = o;
        }

        if (t < TSTEPS - 1) {
            ++phase;
            grid_barrier(bar, NB * phase);
        }
    }
}

extern "C" void kernel_launch(void* const* d_in, const int* in_sizes, int n_in,
                              void* d_out, int out_size, void* d_ws, size_t ws_size,
                              hipStream_t stream)
{
    const float* x    = (const float*)d_in[0];
    const float* h0   = (const float*)d_in[1];
    const float* w_ih = (const float*)d_in[2];
    const float* w_hh = (const float*)d_in[3];
    float* out = (float*)d_out;

    char* ws = (char*)d_ws;
    float* xg       = (float*)ws;
    float* hbufA    = (float*)(ws + XG_BYTES);
    float* hbufB    = (float*)(ws + XG_BYTES + HBUF_BYTES);
    unsigned* bar   = (unsigned*)(ws + XG_BYTES + 2 * HBUF_BYTES);

    hipMemsetAsync(bar, 0, 64, stream);

    dim3 g1(GDIM / 128, (BATCH * TSTEPS) / 128);  // 24 x 128
    xg_gemm_f32<<<g1, 256, 0, stream>>>(x, w_ih, xg);

    gru_recurrence<<<256, 256, 0, stream>>>(h0, w_hh, xg, out, hbufA, hbufB, bar);
}

// Round 2
// 12105.863 us; speedup vs baseline: 1.0829x; 1.0829x over previous
//
#include <hip/hip_runtime.h>
#include <cmath>

// GRU: B=32, T=512, E=512, H=1024, fp32.
// Phase 1: xgt[t][gate][j][b] = sum_e x[b][t][e] * w_ih[gate*1024+j][e]
// Phase 2: persistent kernel, 256 blocks x 512 threads; block i owns h cols
//          [4i,4i+4) and the 12 w_hh rows in (padded) LDS. Grid sync per step
//          via per-block monotonic flags (release store + read-only poll) --
//          no same-line atomic RMW contention.
// h state TRANSPOSED [k][b] in ws, double buffered.

namespace {
constexpr int BATCH  = 32;
constexpr int TSTEPS = 512;
constexpr int EDIM   = 512;
constexpr int HDIM   = 1024;
constexpr int GDIM   = 3 * HDIM;  // 3072

constexpr size_t XG_BYTES   = (size_t)TSTEPS * GDIM * BATCH * 4;  // 192 MiB, [T][3][1024][32]
constexpr size_t HBUF_BYTES = (size_t)HDIM * BATCH * 4;           // 128 KiB
}

// ---------------- Phase 1: xgt = x @ w_ih^T (transposed store) ----------------
// M = 16384 (m = t*32 + b), N = 3072 (g = gate*1024 + j), K = 512.
__global__ __launch_bounds__(256)
void xg_gemm_f32(const float* __restrict__ x, const float* __restrict__ w_ih,
                 float* __restrict__ xgt)
{
    __shared__ float a_s[16 * 132];
    __shared__ float b_s[16 * 132];

    const int tid = threadIdx.x;
    const int n0 = blockIdx.x * 128;
    const int m0 = blockIdx.y * 128;
    const int tx = tid & 15;
    const int ty = tid >> 4;

    float acc[8][8];
    #pragma unroll
    for (int i = 0; i < 8; ++i)
        #pragma unroll
        for (int j = 0; j < 8; ++j) acc[i][j] = 0.f;

    const int r_ld = tid >> 2;         // 0..63
    const int kq4  = (tid & 3) * 4;    // 0,4,8,12

    for (int kc = 0; kc < EDIM; kc += 16) {
        __syncthreads();
        #pragma unroll
        for (int half = 0; half < 2; ++half) {
            const int r = r_ld + half * 64;
            const int m = m0 + r;
            const int bb = m & 31;       // batch
            const int tt = m >> 5;       // time
            float4 av = *(const float4*)&x[((size_t)bb * TSTEPS + tt) * EDIM + kc + kq4];
            a_s[(kq4 + 0) * 132 + r] = av.x;
            a_s[(kq4 + 1) * 132 + r] = av.y;
            a_s[(kq4 + 2) * 132 + r] = av.z;
            a_s[(kq4 + 3) * 132 + r] = av.w;
            const int n = n0 + r;
            float4 bv = *(const float4*)&w_ih[(size_t)n * EDIM + kc + kq4];
            b_s[(kq4 + 0) * 132 + r] = bv.x;
            b_s[(kq4 + 1) * 132 + r] = bv.y;
            b_s[(kq4 + 2) * 132 + r] = bv.z;
            b_s[(kq4 + 3) * 132 + r] = bv.w;
        }
        __syncthreads();
        #pragma unroll
        for (int k = 0; k < 16; ++k) {
            float a_r[8], b_r[8];
            *(float4*)&a_r[0] = *(const float4*)&a_s[k * 132 + ty * 8];
            *(float4*)&a_r[4] = *(const float4*)&a_s[k * 132 + ty * 8 + 4];
            *(float4*)&b_r[0] = *(const float4*)&b_s[k * 132 + tx * 8];
            *(float4*)&b_r[4] = *(const float4*)&b_s[k * 132 + tx * 8 + 4];
            #pragma unroll
            for (int i = 0; i < 8; ++i)
                #pragma unroll
                for (int j = 0; j < 8; ++j)
                    acc[i][j] = fmaf(a_r[i], b_r[j], acc[i][j]);
        }
    }

    // Thread holds m = m0 + ty*8 + i (8 consecutive m = 8 consecutive b within one t).
    const int t  = (m0 >> 5) + (ty >> 2);
    const int b0 = (ty & 3) * 8;
    #pragma unroll
    for (int j = 0; j < 8; ++j) {
        const int g    = n0 + tx * 8 + j;
        const int gate = g >> 10;
        const int jj   = g & 1023;
        float* p = &xgt[(((size_t)t * 3 + gate) * 1024 + jj) * 32 + b0];
        *(float4*)p       = make_float4(acc[0][j], acc[1][j], acc[2][j], acc[3][j]);
        *(float4*)(p + 4) = make_float4(acc[4][j], acc[5][j], acc[6][j], acc[7][j]);
    }
}

// ---------------- Phase 2: persistent GRU recurrence ----------------
// 256 blocks x 512 threads. bgrp = tid&7 (4 batches), jgrp = bit3 (2 j),
// kseg = tid>>4 (32-way k split). acc[gate*2+jj][bb].
__global__ __launch_bounds__(512)
void gru_recurrence(const float* __restrict__ h0, const float* __restrict__ w_hh,
                    const float* __restrict__ xgt, float* __restrict__ out,
                    float* __restrict__ hbufA, float* __restrict__ hbufB,
                    unsigned* __restrict__ flags)
{
    __shared__ float w_s[12 * 1032];           // +8 pad: kills jgrp same-bank hits
    __shared__ float red_s[8 * 2 * 8 * 25];    // [wave][jgrp][bgrp][6*4 + pad]

    const int tid = threadIdx.x;
    const int bid = blockIdx.x;
    const int j0  = bid * 4;

    // Load this block's 12 w_hh rows into LDS (coalesced float4).
    for (int i = tid; i < 12 * 256; i += 512) {
        const int row  = i >> 8;
        const int c4   = (i & 255) * 4;
        const int gate = row >> 2;
        const int jl   = row & 3;
        *(float4*)&w_s[row * 1032 + c4] =
            *(const float4*)&w_hh[((size_t)gate * HDIM + j0 + jl) * HDIM + c4];
    }
    // Transpose h0 -> hbufA[k][b] for our 4 k-rows.
    if (tid < 128) {
        const int k = j0 + (tid >> 5);
        const int b = tid & 31;
        hbufA[k * 32 + b] = h0[(size_t)b * HDIM + k];
    }

    // ---- publish + wait helpers (flag barrier) ----
    auto publish = [&](unsigned val) {
        __syncthreads();  // all block stores drained to L2 (vmcnt0 before s_barrier)
        if (tid == 0)
            __hip_atomic_store(&flags[bid], val, __ATOMIC_RELEASE, __HIP_MEMORY_SCOPE_AGENT);
    };
    auto wait_all = [&](unsigned val) {
        if (tid < 64) {
            for (;;) {
                unsigned a0 = __hip_atomic_load(&flags[tid],       __ATOMIC_RELAXED, __HIP_MEMORY_SCOPE_AGENT);
                unsigned a1 = __hip_atomic_load(&flags[tid + 64],  __ATOMIC_RELAXED, __HIP_MEMORY_SCOPE_AGENT);
                unsigned a2 = __hip_atomic_load(&flags[tid + 128], __ATOMIC_RELAXED, __HIP_MEMORY_SCOPE_AGENT);
                unsigned a3 = __hip_atomic_load(&flags[tid + 192], __ATOMIC_RELAXED, __HIP_MEMORY_SCOPE_AGENT);
                unsigned m01 = a0 < a1 ? a0 : a1;
                unsigned m23 = a2 < a3 ? a2 : a3;
                unsigned mn  = m01 < m23 ? m01 : m23;
                if (__all(mn >= val)) break;
                __builtin_amdgcn_s_sleep(1);
            }
            __builtin_amdgcn_fence(__ATOMIC_ACQUIRE, "agent");  // CU-wide inv
        }
        __syncthreads();
    };

    publish(1u);
    wait_all(1u);

    const int bgrp = tid & 7;
    const int jgrp = (tid >> 3) & 1;
    const int kseg = tid >> 4;        // 0..31
    const int b0   = bgrp * 4;
    const int tjl  = tid >> 5;        // tail j (tid<128)
    const int tb   = tid & 31;        // tail b
    const size_t xgstride = 1024 * 32;

    // Prefetch xg for t=0.
    float xr = 0.f, xz = 0.f, xn = 0.f;
    if (tid < 128) {
        const size_t base = ((size_t)0 * 3 * 1024 + (j0 + tjl)) * 32 + tb;
        xr = xgt[base];
        xz = xgt[base + xgstride];
        xn = xgt[base + 2 * xgstride];
    }

    for (int t = 0; t < TSTEPS; ++t) {
        const float* __restrict__ hcur = (t & 1) ? hbufB : hbufA;
        float* __restrict__ hnxt       = (t & 1) ? hbufA : hbufB;

        float hp = 0.f;
        if (tid < 128) hp = hcur[(j0 + tjl) * 32 + tb];  // issue early

        float acc[6][4];
        #pragma unroll
        for (int r = 0; r < 6; ++r)
            #pragma unroll
            for (int b = 0; b < 4; ++b) acc[r][b] = 0.f;

        #pragma unroll 4
        for (int kk = 0; kk < 32; ++kk) {
            const int k = kk * 32 + kseg;
            const float4 h4 = *(const float4*)&hcur[k * 32 + b0];
            #pragma unroll
            for (int r = 0; r < 6; ++r) {
                const float w = w_s[((r >> 1) * 4 + jgrp * 2 + (r & 1)) * 1032 + k];
                acc[r][0] = fmaf(w, h4.x, acc[r][0]);
                acc[r][1] = fmaf(w, h4.y, acc[r][1]);
                acc[r][2] = fmaf(w, h4.z, acc[r][2]);
                acc[r][3] = fmaf(w, h4.w, acc[r][3]);
            }
        }

        // Reduce over the wave's 4 ksegs (lane bits 4,5).
        #pragma unroll
        for (int r = 0; r < 6; ++r)
            #pragma unroll
            for (int b = 0; b < 4; ++b) {
                float v = acc[r][b];
                v += __shfl_xor(v, 16, 64);
                v += __shfl_xor(v, 32, 64);
                acc[r][b] = v;
            }

        if ((tid & 48) == 0) {  // lanes 0..15 of each wave
            const int wv   = tid >> 6;
            const int base = ((wv * 2 + jgrp) * 8 + bgrp) * 25;
            #pragma unroll
            for (int r = 0; r < 6; ++r)
                #pragma unroll
                for (int b = 0; b < 4; ++b)
                    red_s[base + r * 4 + b] = acc[r][b];
        }
        __syncthreads();

        if (tid < 128) {
            const int jg = tjl >> 1, jj = tjl & 1, bg = tb >> 2, bb = tb & 3;
            float hr = 0.f, hz = 0.f, hn = 0.f;
            #pragma unroll
            for (int w = 0; w < 8; ++w) {
                const float* rs = &red_s[((w * 2 + jg) * 8 + bg) * 25 + bb];
                hr += rs[(0 + jj) * 4];
                hz += rs[(2 + jj) * 4];
                hn += rs[(4 + jj) * 4];
            }
            const float rg   = 1.f / (1.f + expf(-(xr + hr)));
            const float zg   = 1.f / (1.f + expf(-(xz + hz)));
            const float ng   = tanhf(xn + rg * hn);
            const float hnew = (1.f - zg) * ng + zg * hp;
            hnxt[(j0 + tjl) * 32 + tb] = hnew;
            out[((size_t)tb * TSTEPS + t) * HDIM + j0 + tjl] = hnew;

            // Prefetch xg for t+1; loads fly across the barrier.
            if (t + 1 < TSTEPS) {
                const size_t base2 = ((size_t)(t + 1) * 3 * 1024 + (j0 + tjl)) * 32 + tb;
                xr = xgt[base2];
                xz = xgt[base2 + xgstride];
                xn = xgt[base2 + 2 * xgstride];
            }
        }

        if (t + 1 < TSTEPS) {
            publish((unsigned)(t + 2));
            wait_all((unsigned)(t + 2));
        }
    }
}

extern "C" void kernel_launch(void* const* d_in, const int* in_sizes, int n_in,
                              void* d_out, int out_size, void* d_ws, size_t ws_size,
                              hipStream_t stream)
{
    const float* x    = (const float*)d_in[0];
    const float* h0   = (const float*)d_in[1];
    const float* w_ih = (const float*)d_in[2];
    const float* w_hh = (const float*)d_in[3];
    float* out = (float*)d_out;

    char* ws = (char*)d_ws;
    float* xgt      = (float*)ws;
    float* hbufA    = (float*)(ws + XG_BYTES);
    float* hbufB    = (float*)(ws + XG_BYTES + HBUF_BYTES);
    unsigned* flags = (unsigned*)(ws + XG_BYTES + 2 * HBUF_BYTES);

    hipMemsetAsync(flags, 0, 256 * sizeof(unsigned), stream);

    dim3 g1(GDIM / 128, (BATCH * TSTEPS) / 128);  // 24 x 128
    xg_gemm_f32<<<g1, 256, 0, stream>>>(x, w_ih, xgt);

    gru_recurrence<<<256, 512, 0, stream>>>(h0, w_hh, xgt, out, hbufA, hbufB, flags);
}

// Round 3
// 12043.337 us; speedup vs baseline: 1.0886x; 1.0052x over previous
//
#include <hip/hip_runtime.h>
#include <cmath>

// GRU: B=32, T=512, E=512, H=1024, fp32.
// Phase 1: xgt[t][gate][j][b] = sum_e x[b][t][e] * w_ih[gate*1024+j][e]
// Phase 2: persistent kernel, 256 blocks x 512 threads; block i owns h cols
//          [4i,4i+4) and the 12 w_hh rows in (padded) LDS. Grid sync per step
//          via per-block monotonic flags (release store + read-only poll) --
//          no same-line atomic RMW contention.
// h state TRANSPOSED [k][b] in ws, double buffered.

namespace {
constexpr int BATCH  = 32;
constexpr int TSTEPS = 512;
constexpr int EDIM   = 512;
constexpr int HDIM   = 1024;
constexpr int GDIM   = 3 * HDIM;  // 3072

constexpr size_t XG_BYTES   = (size_t)TSTEPS * GDIM * BATCH * 4;  // 192 MiB, [T][3][1024][32]
constexpr size_t HBUF_BYTES = (size_t)HDIM * BATCH * 4;           // 128 KiB
}

// ---------------- Phase 1: xgt = x @ w_ih^T (transposed store) ----------------
// M = 16384 (m = t*32 + b), N = 3072 (g = gate*1024 + j), K = 512.
__global__ __launch_bounds__(256)
void xg_gemm_f32(const float* __restrict__ x, const float* __restrict__ w_ih,
                 float* __restrict__ xgt)
{
    __shared__ float a_s[16 * 132];
    __shared__ float b_s[16 * 132];

    const int tid = threadIdx.x;
    const int n0 = blockIdx.x * 128;
    const int m0 = blockIdx.y * 128;
    const int tx = tid & 15;
    const int ty = tid >> 4;

    float acc[8][8];
    #pragma unroll
    for (int i = 0; i < 8; ++i)
        #pragma unroll
        for (int j = 0; j < 8; ++j) acc[i][j] = 0.f;

    const int r_ld = tid >> 2;         // 0..63
    const int kq4  = (tid & 3) * 4;    // 0,4,8,12

    for (int kc = 0; kc < EDIM; kc += 16) {
        __syncthreads();
        #pragma unroll
        for (int half = 0; half < 2; ++half) {
            const int r = r_ld + half * 64;
            const int m = m0 + r;
            const int bb = m & 31;       // batch
            const int tt = m >> 5;       // time
            float4 av = *(const float4*)&x[((size_t)bb * TSTEPS + tt) * EDIM + kc + kq4];
            a_s[(kq4 + 0) * 132 + r] = av.x;
            a_s[(kq4 + 1) * 132 + r] = av.y;
            a_s[(kq4 + 2) * 132 + r] = av.z;
            a_s[(kq4 + 3) * 132 + r] = av.w;
            const int n = n0 + r;
            float4 bv = *(const float4*)&w_ih[(size_t)n * EDIM + kc + kq4];
            b_s[(kq4 + 0) * 132 + r] = bv.x;
            b_s[(kq4 + 1) * 132 + r] = bv.y;
            b_s[(kq4 + 2) * 132 + r] = bv.z;
            b_s[(kq4 + 3) * 132 + r] = bv.w;
        }
        __syncthreads();
        #pragma unroll
        for (int k = 0; k < 16; ++k) {
            float a_r[8], b_r[8];
            *(float4*)&a_r[0] = *(const float4*)&a_s[k * 132 + ty * 8];
            *(float4*)&a_r[4] = *(const float4*)&a_s[k * 132 + ty * 8 + 4];
            *(float4*)&b_r[0] = *(const float4*)&b_s[k * 132 + tx * 8];
            *(float4*)&b_r[4] = *(const float4*)&b_s[k * 132 + tx * 8 + 4];
            #pragma unroll
            for (int i = 0; i < 8; ++i)
                #pragma unroll
                for (int j = 0; j < 8; ++j)
                    acc[i][j] = fmaf(a_r[i], b_r[j], acc[i][j]);
        }
    }

    // Thread holds m = m0 + ty*8 + i (8 consecutive m = 8 consecutive b within one t).
    const int t  = (m0 >> 5) + (ty >> 2);
    const int b0 = (ty & 3) * 8;
    #pragma unroll
    for (int j = 0; j < 8; ++j) {
        const int g    = n0 + tx * 8 + j;
        const int gate = g >> 10;
        const int jj   = g & 1023;
        float* p = &xgt[(((size_t)t * 3 + gate) * 1024 + jj) * 32 + b0];
        *(float4*)p       = make_float4(acc[0][j], acc[1][j], acc[2][j], acc[3][j]);
        *(float4*)(p + 4) = make_float4(acc[4][j], acc[5][j], acc[6][j], acc[7][j]);
    }
}

// ---------------- Phase 2: persistent GRU recurrence ----------------
// 256 blocks x 512 threads. bgrp = tid&7 (4 batches), jgrp = bit3 (2 j),
// kseg = tid>>4 (32-way k split). acc[gate*2+jj][bb].
__global__ __launch_bounds__(512)
void gru_recurrence(const float* __restrict__ h0, const float* __restrict__ w_hh,
                    const float* __restrict__ xgt, float* __restrict__ out,
                    float* __restrict__ hbufA, float* __restrict__ hbufB,
                    unsigned* __restrict__ flags)
{
    __shared__ float w_s[12 * 1032];           // +8 pad: kills jgrp same-bank hits
    __shared__ float red_s[8 * 2 * 8 * 25];    // [wave][jgrp][bgrp][6*4 + pad]

    const int tid = threadIdx.x;
    const int bid = blockIdx.x;
    const int j0  = bid * 4;

    // Load this block's 12 w_hh rows into LDS (coalesced float4).
    for (int i = tid; i < 12 * 256; i += 512) {
        const int row  = i >> 8;
        const int c4   = (i & 255) * 4;
        const int gate = row >> 2;
        const int jl   = row & 3;
        *(float4*)&w_s[row * 1032 + c4] =
            *(const float4*)&w_hh[((size_t)gate * HDIM + j0 + jl) * HDIM + c4];
    }
    // Transpose h0 -> hbufA[k][b] for our 4 k-rows.
    if (tid < 128) {
        const int k = j0 + (tid >> 5);
        const int b = tid & 31;
        hbufA[k * 32 + b] = h0[(size_t)b * HDIM + k];
    }

    // ---- publish + wait helpers (flag barrier) ----
    auto publish = [&](unsigned val) {
        __syncthreads();  // all block stores drained to L2 (vmcnt0 before s_barrier)
        if (tid == 0)
            __hip_atomic_store(&flags[bid], val, __ATOMIC_RELEASE, __HIP_MEMORY_SCOPE_AGENT);
    };
    auto wait_all = [&](unsigned val) {
        if (tid < 64) {
            for (;;) {
                unsigned a0 = __hip_atomic_load(&flags[tid],       __ATOMIC_RELAXED, __HIP_MEMORY_SCOPE_AGENT);
                unsigned a1 = __hip_atomic_load(&flags[tid + 64],  __ATOMIC_RELAXED, __HIP_MEMORY_SCOPE_AGENT);
                unsigned a2 = __hip_atomic_load(&flags[tid + 128], __ATOMIC_RELAXED, __HIP_MEMORY_SCOPE_AGENT);
                unsigned a3 = __hip_atomic_load(&flags[tid + 192], __ATOMIC_RELAXED, __HIP_MEMORY_SCOPE_AGENT);
                unsigned m01 = a0 < a1 ? a0 : a1;
                unsigned m23 = a2 < a3 ? a2 : a3;
                unsigned mn  = m01 < m23 ? m01 : m23;
                if (__all(mn >= val)) break;
                __builtin_amdgcn_s_sleep(1);
            }
            __builtin_amdgcn_fence(__ATOMIC_ACQUIRE, "agent");  // CU-wide inv
        }
        __syncthreads();
    };

    publish(1u);
    wait_all(1u);

    const int bgrp = tid & 7;
    const int jgrp = (tid >> 3) & 1;
    const int kseg = tid >> 4;        // 0..31
    const int b0   = bgrp * 4;
    const int tjl  = tid >> 5;        // tail j (tid<128)
    const int tb   = tid & 31;        // tail b
    const size_t xgstride = 1024 * 32;

    // Prefetch xg for t=0.
    float xr = 0.f, xz = 0.f, xn = 0.f;
    if (tid < 128) {
        const size_t base = ((size_t)0 * 3 * 1024 + (j0 + tjl)) * 32 + tb;
        xr = xgt[base];
        xz = xgt[base + xgstride];
        xn = xgt[base + 2 * xgstride];
    }

    for (int t = 0; t < TSTEPS; ++t) {
        const float* __restrict__ hcur = (t & 1) ? hbufB : hbufA;
        float* __restrict__ hnxt       = (t & 1) ? hbufA : hbufB;

        float hp = 0.f;
        if (tid < 128) hp = hcur[(j0 + tjl) * 32 + tb];  // issue early

        float acc[6][4];
        #pragma unroll
        for (int r = 0; r < 6; ++r)
            #pragma unroll
            for (int b = 0; b < 4; ++b) acc[r][b] = 0.f;

        #pragma unroll 4
        for (int kk = 0; kk < 32; ++kk) {
            const int k = kk * 32 + kseg;
            const float4 h4 = *(const float4*)&hcur[k * 32 + b0];
            #pragma unroll
            for (int r = 0; r < 6; ++r) {
                const float w = w_s[((r >> 1) * 4 + jgrp * 2 + (r & 1)) * 1032 + k];
                acc[r][0] = fmaf(w, h4.x, acc[r][0]);
                acc[r][1] = fmaf(w, h4.y, acc[r][1]);
                acc[r][2] = fmaf(w, h4.z, acc[r][2]);
                acc[r][3] = fmaf(w, h4.w, acc[r][3]);
            }
        }

        // Reduce over the wave's 4 ksegs (lane bits 4,5).
        #pragma unroll
        for (int r = 0; r < 6; ++r)
            #pragma unroll
            for (int b = 0; b < 4; ++b) {
                float v = acc[r][b];
                v += __shfl_xor(v, 16, 64);
                v += __shfl_xor(v, 32, 64);
                acc[r][b] = v;
            }

        if ((tid & 48) == 0) {  // lanes 0..15 of each wave
            const int wv   = tid >> 6;
            const int base = ((wv * 2 + jgrp) * 8 + bgrp) * 25;
            #pragma unroll
            for (int r = 0; r < 6; ++r)
                #pragma unroll
                for (int b = 0; b < 4; ++b)
                    red_s[base + r * 4 + b] = acc[r][b];
        }
        __syncthreads();

        if (tid < 128) {
            const int jg = tjl >> 1, jj = tjl & 1, bg = tb >> 2, bb = tb & 3;
            float hr = 0.f, hz = 0.f, hn = 0.f;
            #pragma unroll
            for (int w = 0; w < 8; ++w) {
                const float* rs = &red_s[((w * 2 + jg) * 8 + bg) * 25 + bb];
                hr += rs[(0 + jj) * 4];
                hz += rs[(2 + jj) * 4];
                hn += rs[(4 + jj) * 4];
            }
            const float rg   = 1.f / (1.f + expf(-(xr + hr)));
            const float zg   = 1.f / (1.f + expf(-(xz + hz)));
            const float ng   = tanhf(xn + rg * hn);
            const float hnew = (1.f - zg) * ng + zg * hp;
            hnxt[(j0 + tjl) * 32 + tb] = hnew;
            out[((size_t)tb * TSTEPS + t) * HDIM + j0 + tjl] = hnew;

            // Prefetch xg for t+1; loads fly across the barrier.
            if (t + 1 < TSTEPS) {
                const size_t base2 = ((size_t)(t + 1) * 3 * 1024 + (j0 + tjl)) * 32 + tb;
                xr = xgt[base2];
                xz = xgt[base2 + xgstride];
                xn = xgt[base2 + 2 * xgstride];
            }
        }

        if (t + 1 < TSTEPS) {
            publish((unsigned)(t + 2));
            wait_all((unsigned)(t + 2));
        }
    }
}

extern "C" void kernel_launch(void* const* d_in, const int* in_sizes, int n_in,
                              void* d_out, int out_size, void* d_ws, size_t ws_size,
                              hipStream_t stream)
{
    const float* x    = (const float*)d_in[0];
    const float* h0   = (const float*)d_in[1];
    const float* w_ih = (const float*)d_in[2];
    const float* w_hh = (const float*)d_in[3];
    float* out = (float*)d_out;

    char* ws = (char*)d_ws;
    float* xgt      = (float*)ws;
    float* hbufA    = (float*)(ws + XG_BYTES);
    float* hbufB    = (float*)(ws + XG_BYTES + HBUF_BYTES);
    unsigned* flags = (unsigned*)(ws + XG_BYTES + 2 * HBUF_BYTES);

    hipMemsetAsync(flags, 0, 256 * sizeof(unsigned), stream);

    dim3 g1(GDIM / 128, (BATCH * TSTEPS) / 128);  // 24 x 128
    xg_gemm_f32<<<g1, 256, 0, stream>>>(x, w_ih, xgt);

    gru_recurrence<<<256, 512, 0, stream>>>(h0, w_hh, xgt, out, hbufA, hbufB, flags);
}

// Round 4
// 4389.460 us; speedup vs baseline: 2.9867x; 2.7437x over previous
//
#include <hip/hip_runtime.h>
#include <cmath>

// GRU: B=32, T=512, E=512, H=1024, fp32.
// Phase 1: xgt[t][gate][j][b] = x @ w_ih^T (transposed store)
// Phase 2: persistent kernel, 256 blocks x 1024 threads; block i owns h cols
//          [4i,4i+4) and its 12 w_hh rows in padded LDS.
//          ALL cross-block traffic (h state, flags) uses relaxed agent-scope
//          atomics (sc0 sc1: bypass L1/L2, coherent at L3). No fences ->
//          no wbL2 flush, no L2 invalidate per step.
// h state TRANSPOSED [k][b] in ws, double buffered.

namespace {
constexpr int BATCH  = 32;
constexpr int TSTEPS = 512;
constexpr int EDIM   = 512;
constexpr int HDIM   = 1024;
constexpr int GDIM   = 3 * HDIM;  // 3072

constexpr size_t XG_BYTES   = (size_t)TSTEPS * GDIM * BATCH * 4;  // 192 MiB
constexpr size_t HBUF_BYTES = (size_t)HDIM * BATCH * 4;           // 128 KiB
}

// ---------------- Phase 1: xgt = x @ w_ih^T ----------------
__global__ __launch_bounds__(256)
void xg_gemm_f32(const float* __restrict__ x, const float* __restrict__ w_ih,
                 float* __restrict__ xgt)
{
    __shared__ float a_s[16 * 132];
    __shared__ float b_s[16 * 132];

    const int tid = threadIdx.x;
    const int n0 = blockIdx.x * 128;
    const int m0 = blockIdx.y * 128;
    const int tx = tid & 15;
    const int ty = tid >> 4;

    float acc[8][8];
    #pragma unroll
    for (int i = 0; i < 8; ++i)
        #pragma unroll
        for (int j = 0; j < 8; ++j) acc[i][j] = 0.f;

    const int r_ld = tid >> 2;
    const int kq4  = (tid & 3) * 4;

    for (int kc = 0; kc < EDIM; kc += 16) {
        __syncthreads();
        #pragma unroll
        for (int half = 0; half < 2; ++half) {
            const int r = r_ld + half * 64;
            const int m = m0 + r;
            const int bb = m & 31;
            const int tt = m >> 5;
            float4 av = *(const float4*)&x[((size_t)bb * TSTEPS + tt) * EDIM + kc + kq4];
            a_s[(kq4 + 0) * 132 + r] = av.x;
            a_s[(kq4 + 1) * 132 + r] = av.y;
            a_s[(kq4 + 2) * 132 + r] = av.z;
            a_s[(kq4 + 3) * 132 + r] = av.w;
            const int n = n0 + r;
            float4 bv = *(const float4*)&w_ih[(size_t)n * EDIM + kc + kq4];
            b_s[(kq4 + 0) * 132 + r] = bv.x;
            b_s[(kq4 + 1) * 132 + r] = bv.y;
            b_s[(kq4 + 2) * 132 + r] = bv.z;
            b_s[(kq4 + 3) * 132 + r] = bv.w;
        }
        __syncthreads();
        #pragma unroll
        for (int k = 0; k < 16; ++k) {
            float a_r[8], b_r[8];
            *(float4*)&a_r[0] = *(const float4*)&a_s[k * 132 + ty * 8];
            *(float4*)&a_r[4] = *(const float4*)&a_s[k * 132 + ty * 8 + 4];
            *(float4*)&b_r[0] = *(const float4*)&b_s[k * 132 + tx * 8];
            *(float4*)&b_r[4] = *(const float4*)&b_s[k * 132 + tx * 8 + 4];
            #pragma unroll
            for (int i = 0; i < 8; ++i)
                #pragma unroll
                for (int j = 0; j < 8; ++j)
                    acc[i][j] = fmaf(a_r[i], b_r[j], acc[i][j]);
        }
    }

    const int t  = (m0 >> 5) + (ty >> 2);
    const int b0 = (ty & 3) * 8;
    #pragma unroll
    for (int j = 0; j < 8; ++j) {
        const int g    = n0 + tx * 8 + j;
        const int gate = g >> 10;
        const int jj   = g & 1023;
        float* p = &xgt[(((size_t)t * 3 + gate) * 1024 + jj) * 32 + b0];
        *(float4*)p       = make_float4(acc[0][j], acc[1][j], acc[2][j], acc[3][j]);
        *(float4*)(p + 4) = make_float4(acc[4][j], acc[5][j], acc[6][j], acc[7][j]);
    }
}

// ---------------- Phase 2: persistent GRU recurrence ----------------
// 1024 threads: bgrp = tid&15 (2 b), jgrp = bit4 (2 j), kseg = tid>>5 (32 k each).
__global__ __launch_bounds__(1024, 4)
void gru_recurrence(const float* __restrict__ h0, const float* __restrict__ w_hh,
                    const float* __restrict__ xgt, float* __restrict__ out,
                    float* __restrict__ hbufA, float* __restrict__ hbufB,
                    unsigned* __restrict__ flags)
{
    __shared__ float w_s[12 * 1032];            // 49.5 KB, +8 pad
    __shared__ float red_s[16 * 2 * 16 * 13];   // 26.6 KB [wave][jgrp][bgrp][12+1]

    const int tid = threadIdx.x;
    const int bid = blockIdx.x;
    const int j0  = bid * 4;

    // Load this block's 12 w_hh rows into LDS.
    for (int i = tid; i < 12 * 256; i += 1024) {
        const int row  = i >> 8;
        const int c4   = (i & 255) * 4;
        const int gate = row >> 2;
        const int jl   = row & 3;
        *(float4*)&w_s[row * 1032 + c4] =
            *(const float4*)&w_hh[((size_t)gate * HDIM + j0 + jl) * HDIM + c4];
    }

    const int tjl = tid >> 5;   // tail j (tid<128)
    const int tb  = tid & 31;   // tail b

    // h0 transpose -> hbufA (write-through atomics; consumed by all blocks)
    // and own-slice hp kept in register.
    float hp = 0.f;
    if (tid < 128) {
        hp = h0[(size_t)tb * HDIM + j0 + tjl];
        __hip_atomic_store(&hbufA[(j0 + tjl) * 32 + tb], hp,
                           __ATOMIC_RELAXED, __HIP_MEMORY_SCOPE_AGENT);
    }

    auto publish = [&](unsigned val) {
        __syncthreads();  // drains vmcnt for all waves before flag store
        if (tid == 0)
            __hip_atomic_store(&flags[bid * 8], val,
                               __ATOMIC_RELAXED, __HIP_MEMORY_SCOPE_AGENT);
    };
    auto wait_all = [&](unsigned val) {
        if (tid < 256) {
            const unsigned* fp = &flags[tid * 8];
            while (__hip_atomic_load(fp, __ATOMIC_RELAXED, __HIP_MEMORY_SCOPE_AGENT) < val)
                __builtin_amdgcn_s_sleep(2);
        }
        __syncthreads();
    };

    publish(1u);
    wait_all(1u);

    const int bgrp = tid & 15;
    const int jgrp = (tid >> 4) & 1;
    const int kseg = tid >> 5;        // 0..31
    const int b0   = bgrp * 2;
    const size_t xgstride = 1024 * 32;

    // Prefetch xg for t=0 (normal cached loads; read-only data).
    float xr = 0.f, xz = 0.f, xn = 0.f;
    if (tid < 128) {
        const size_t base = (size_t)(j0 + tjl) * 32 + tb;
        xr = xgt[base];
        xz = xgt[base + xgstride];
        xn = xgt[base + 2 * xgstride];
    }

    for (int t = 0; t < TSTEPS; ++t) {
        const float* __restrict__ hcur = (t & 1) ? hbufB : hbufA;
        float* __restrict__ hnxt       = (t & 1) ? hbufA : hbufB;

        float acc[6][2];
        #pragma unroll
        for (int r = 0; r < 6; ++r) { acc[r][0] = 0.f; acc[r][1] = 0.f; }

        #pragma unroll 8
        for (int kk = 0; kk < 32; ++kk) {
            const int k = kk * 32 + kseg;
            unsigned long long hv = __hip_atomic_load(
                (const unsigned long long*)&hcur[k * 32 + b0],
                __ATOMIC_RELAXED, __HIP_MEMORY_SCOPE_AGENT);
            const float hf0 = __uint_as_float((unsigned)hv);
            const float hf1 = __uint_as_float((unsigned)(hv >> 32));
            #pragma unroll
            for (int r = 0; r < 6; ++r) {
                const float w = w_s[((r >> 1) * 4 + jgrp * 2 + (r & 1)) * 1032 + k];
                acc[r][0] = fmaf(w, hf0, acc[r][0]);
                acc[r][1] = fmaf(w, hf1, acc[r][1]);
            }
        }

        // Pair-reduce the two ksegs within each wave (lane bit 5).
        #pragma unroll
        for (int r = 0; r < 6; ++r)
            #pragma unroll
            for (int b = 0; b < 2; ++b) {
                float v = acc[r][b];
                v += __shfl_xor(v, 32, 64);
                acc[r][b] = v;
            }

        const int lane = tid & 63;
        if (lane < 32) {
            const int wv = tid >> 6;
            const int jg = (lane >> 4) & 1;
            const int bg = lane & 15;
            const int base = ((wv * 2 + jg) * 16 + bg) * 13;
            #pragma unroll
            for (int r = 0; r < 6; ++r) {
                red_s[base + r * 2 + 0] = acc[r][0];
                red_s[base + r * 2 + 1] = acc[r][1];
            }
        }
        __syncthreads();

        if (tid < 128) {
            const int jg = tjl >> 1, jj = tjl & 1, bg = tb >> 1, bb = tb & 1;
            float hr = 0.f, hz = 0.f, hn = 0.f;
            #pragma unroll
            for (int wv = 0; wv < 16; ++wv) {
                const float* rs = &red_s[((wv * 2 + jg) * 16 + bg) * 13 + bb];
                hr += rs[(0 + jj) * 2];
                hz += rs[(2 + jj) * 2];
                hn += rs[(4 + jj) * 2];
            }
            const float rg   = 1.f / (1.f + expf(-(xr + hr)));
            const float zg   = 1.f / (1.f + expf(-(xz + hz)));
            const float ng   = tanhf(xn + rg * hn);
            const float hnew = (1.f - zg) * ng + zg * hp;
            hp = hnew;  // own slice, same thread next step
            __hip_atomic_store(&hnxt[(j0 + tjl) * 32 + tb], hnew,
                               __ATOMIC_RELAXED, __HIP_MEMORY_SCOPE_AGENT);
            out[((size_t)tb * TSTEPS + t) * HDIM + j0 + tjl] = hnew;

            // Prefetch xg for t+1 (flies across the barrier).
            if (t + 1 < TSTEPS) {
                const size_t base2 = ((size_t)(t + 1) * 3 * 1024 + (j0 + tjl)) * 32 + tb;
                xr = xgt[base2];
                xz = xgt[base2 + xgstride];
                xn = xgt[base2 + 2 * xgstride];
            }
        }

        if (t + 1 < TSTEPS) {
            publish((unsigned)(t + 2));
            wait_all((unsigned)(t + 2));
        }
    }
}

extern "C" void kernel_launch(void* const* d_in, const int* in_sizes, int n_in,
                              void* d_out, int out_size, void* d_ws, size_t ws_size,
                              hipStream_t stream)
{
    const float* x    = (const float*)d_in[0];
    const float* h0   = (const float*)d_in[1];
    const float* w_ih = (const float*)d_in[2];
    const float* w_hh = (const float*)d_in[3];
    float* out = (float*)d_out;

    char* ws = (char*)d_ws;
    float* xgt      = (float*)ws;
    float* hbufA    = (float*)(ws + XG_BYTES);
    float* hbufB    = (float*)(ws + XG_BYTES + HBUF_BYTES);
    unsigned* flags = (unsigned*)(ws + XG_BYTES + 2 * HBUF_BYTES);

    hipMemsetAsync(flags, 0, 256 * 8 * sizeof(unsigned), stream);

    dim3 g1(GDIM / 128, (BATCH * TSTEPS) / 128);  // 24 x 128
    xg_gemm_f32<<<g1, 256, 0, stream>>>(x, w_ih, xgt);

    gru_recurrence<<<256, 1024, 0, stream>>>(h0, w_hh, xgt, out, hbufA, hbufB, flags);
}